// Round 1
// baseline (742.246 us; speedup 1.0000x reference)
//
#include <hip/hip_runtime.h>
#include <math.h>

// SubglacialDrainageSystem: 64x64 grid, N=4096 nodes, L=8064 links.
// Replace the reference's dense 4096x4096 solve with matrix-free
// Jacobi-preconditioned CG on the 5-point graph Laplacian, run entirely
// inside ONE workgroup (1024 threads, 4 nodes/thread, p-vector in LDS).
// CG in fp64 for robustness; matrix assembly in fp32 matching reference.

#define NT   1024
#define KPER 4          // nodes per thread; requires N <= NT*KPER (= 4096)
#define NMAX (NT * KPER)

__device__ __forceinline__ double block_reduce(double v, double* red) {
    // full-wave (64-lane) shuffle reduce
    for (int off = 32; off > 0; off >>= 1)
        v += __shfl_down(v, off, 64);
    const int lane = threadIdx.x & 63;
    const int wid  = threadIdx.x >> 6;
    __syncthreads();                 // protect red[] reuse across calls
    if (lane == 0) red[wid] = v;
    __syncthreads();
    if (threadIdx.x < 64) {
        double s = (threadIdx.x < (NT / 64)) ? red[threadIdx.x] : 0.0;
        for (int off = 8; off > 0; off >>= 1)
            s += __shfl_down(s, off, 64);
        if (threadIdx.x == 0) red[16] = s;
    }
    __syncthreads();
    return red[16];
}

__global__ __launch_bounds__(NT, 1)
void sds_solver(const float* __restrict__ base_pot,
                const float* __restrict__ ovb,
                const float* __restrict__ melt,
                const float* __restrict__ sheet,
                const float* __restrict__ pot,
                const float* __restrict__ svel,
                const float* __restrict__ llen,
                const int*   __restrict__ ltail,
                const int*   __restrict__ lhead,
                const int*   __restrict__ lan,
                const int*   __restrict__ inflow,
                const int*   __restrict__ dt_raw,
                float* __restrict__ out,
                int N, int L)
{
    __shared__ double p_sh[NMAX];    // CG search vector (fp64, 32 KB)
    __shared__ double red[20];
    // link coefficients staged in the SAME LDS (dead after node setup):
    // 8064 floats = 32256 B <= 32768 B of p_sh.
    float* c_sh = reinterpret_cast<float*>(p_sh);

    const int tid = threadIdx.x;

    // dt arrives as a 1-element array; robust to int32 or float32 encoding.
    const int dti = dt_raw[0];
    const float as_f = __int_as_float(dti);
    const double dtf = (as_f > 0.5f && as_f < 1.0e12f) ? (double)as_f : (double)dti;

    // ---- per-link coefficient c = -K * sheets^1.25 * len * |grad|^-0.5 ----
    for (int l = tid; l < L; l += NT) {
        const int t = ltail[l], h = lhead[l];
        const float sheets = 0.5f * (sheet[t] + sheet[h]);
        const float len = llen[l];
        const float grad = fabsf((pot[t] - pot[h]) / len);
        c_sh[l] = -0.01f * powf(sheets, 1.25f) * len / sqrtf(grad);
    }
    __syncthreads();

    // ---- per-node setup (4 nodes/thread, strided) ----
    int    nbr[KPER][4];
    float  coef[KPER][4];
    double diag[KPER], invd[KPER], xv[KPER], rv[KPER], pv[KPER], zv[KPER];
    double bb[KPER];

    for (int k = 0; k < KPER; ++k) {
        const int n = tid + k * NT;
        double d = 0.0, g = 0.0, b = 0.0, x0 = 0.0;
        bool dir = false;
        if (n < N) {
            dir = (inflow[n] == 1);
            g = (double)base_pot[n] - (double)ovb[n];
        }
        for (int j = 0; j < 4; ++j) {
            float c = 0.0f; int nb = 0;
            if (n < N) {
                const int l = lan[n * 4 + j];
                if (l >= 0 && !dir) {
                    c  = c_sh[l];
                    nb = ltail[l] + lhead[l] - n;
                    d -= (double)c;
                }
            }
            coef[k][j] = c;
            nbr[k][j]  = nb;
        }
        if (n < N) {
            b  = dir ? g : (double)melt[n];
            x0 = dir ? g : 0.0;
        }
        diag[k] = (dir || n >= N || d == 0.0) ? 1.0 : d;
        invd[k] = 1.0 / diag[k];
        bb[k]   = b;
        xv[k]   = x0;
    }
    __syncthreads();                       // last read of c_sh done
    for (int k = 0; k < KPER; ++k) {
        const int n = tid + k * NT;
        if (n < N) p_sh[n] = xv[k];        // x0 (Dirichlet lift)
    }
    __syncthreads();

    // ---- r0 = b - A x0 ; z = r/diag ; p = z ----
    double rz_part = 0.0;
    for (int k = 0; k < KPER; ++k) {
        double s = diag[k] * xv[k];
        for (int j = 0; j < 4; ++j)
            s += (double)coef[k][j] * p_sh[nbr[k][j]];
        const int n = tid + k * NT;
        rv[k] = (n < N) ? (bb[k] - s) : 0.0;
        zv[k] = rv[k] * invd[k];
        pv[k] = zv[k];
        rz_part += rv[k] * zv[k];
    }
    double rz = block_reduce(rz_part, red);   // final barrier = x0-read fence
    for (int k = 0; k < KPER; ++k) {
        const int n = tid + k * NT;
        if (n < N) p_sh[n] = pv[k];
    }
    __syncthreads();

    const double tol = rz * 1e-14 + 1e-300;

    // ---- Jacobi-PCG main loop ----
    for (int it = 0; it < 1000; ++it) {
        double Ap[KPER];
        double pap_part = 0.0;
        for (int k = 0; k < KPER; ++k) {
            double s = diag[k] * pv[k];
            for (int j = 0; j < 4; ++j)
                s += (double)coef[k][j] * p_sh[nbr[k][j]];
            Ap[k] = s;
            pap_part += pv[k] * s;
        }
        const double pAp = block_reduce(pap_part, red);
        if (!(pAp > 0.0)) break;           // uniform (broadcast value)
        const double alpha = rz / pAp;

        double rzn_part = 0.0;
        for (int k = 0; k < KPER; ++k) {
            xv[k] += alpha * pv[k];
            rv[k] -= alpha * Ap[k];
            zv[k]  = rv[k] * invd[k];
            rzn_part += rv[k] * zv[k];
        }
        const double rzn = block_reduce(rzn_part, red);
        if (rzn <= tol || !(rzn == rzn)) break;   // converged / NaN, uniform

        const double beta = rzn / rz;
        rz = rzn;
        // block_reduce's trailing barrier fences all SpMV reads of p_sh
        for (int k = 0; k < KPER; ++k) {
            pv[k] = zv[k] + beta * pv[k];
            const int n = tid + k * NT;
            if (n < N) p_sh[n] = pv[k];
        }
        __syncthreads();
    }

    // ---- epilogue: write new_potential, compute new_h ----
    for (int k = 0; k < KPER; ++k) {
        const int n = tid + k * NT;
        if (n >= N) continue;
        const double x = xv[k];
        out[n] = (float)x;

        float sv = 0.0f; int cnt = 0;
        for (int j = 0; j < 4; ++j) {
            const int l = lan[n * 4 + j];
            if (l >= 0) { sv += svel[l]; cnt++; }
        }
        const double sliding =
            fabs((double)sv / 31556926.0 / (double)(cnt > 0 ? cnt : 1));
        const double P   = (double)base_pot[n] - x;
        const double num = (double)sheet[n] + dtf * sliding * 0.1 / 2.0;
        const double den = 1.0 + dtf * (sliding / 2.0 + 5e-25 * P * P * P);
        out[N + n] = (float)(num / den);
    }
}

extern "C" void kernel_launch(void* const* d_in, const int* in_sizes, int n_in,
                              void* d_out, int out_size, void* d_ws, size_t ws_size,
                              hipStream_t stream) {
    const float* base_pot = (const float*)d_in[0];
    const float* ovb      = (const float*)d_in[1];
    const float* melt     = (const float*)d_in[2];
    const float* sheet    = (const float*)d_in[3];
    const float* pot      = (const float*)d_in[4];
    const float* svel     = (const float*)d_in[5];
    const float* llen     = (const float*)d_in[6];
    const int*   ltail    = (const int*)d_in[7];
    const int*   lhead    = (const int*)d_in[8];
    const int*   lan      = (const int*)d_in[9];
    const int*   inflow   = (const int*)d_in[10];
    const int*   dt_raw   = (const int*)d_in[11];
    float* out = (float*)d_out;
    const int N = in_sizes[0];
    const int L = in_sizes[5];

    hipLaunchKernelGGL(sds_solver, dim3(1), dim3(NT), 0, stream,
                       base_pot, ovb, melt, sheet, pot, svel, llen,
                       ltail, lhead, lan, inflow, dt_raw, out, N, L);
}